// Round 5
// baseline (3953.740 us; speedup 1.0000x reference)
//
#include <hip/hip_runtime.h>
#include <stdint.h>

using u8  = unsigned char;
using s8  = signed char;
using u16 = unsigned short;
using u32 = unsigned int;
using u64 = unsigned long long;

typedef int   v4i __attribute__((ext_vector_type(4)));
typedef float v4f __attribute__((ext_vector_type(4)));
typedef short v8s __attribute__((ext_vector_type(8)));

__device__ __forceinline__ u16 f2bf(float f){
  u32 u = __builtin_bit_cast(u32, f);
  u32 r = (u + 0x7FFFu + ((u >> 16) & 1u)) >> 16;
  return (u16)r;
}
__device__ __forceinline__ float bf2f(u16 b){
  u32 u = ((u32)b) << 16;
  return __builtin_bit_cast(float, u);
}

// ---------------------------------------------------------------------------
// Quantize fp32 -> 4 signed-i8 digit planes of X = rint(x*scale). Exact.
// ---------------------------------------------------------------------------
__global__ __launch_bounds__(256) void quant_digits(
    const float* __restrict__ in, s8* __restrict__ dig, int n, float scale, float clampv)
{
  int t = blockIdx.x * 256 + threadIdx.x;
  int n8 = n >> 3;
  if (t >= n8) return;
  const float4* inv = (const float4*)in;
  float4 a = inv[2*t], b = inv[2*t+1];
  float xs[8] = {a.x,a.y,a.z,a.w,b.x,b.y,b.z,b.w};
  u64 p0=0,p1=0,p2=0,p3=0;
#pragma unroll
  for (int j=0;j<8;j++){
    float xv = fminf(fmaxf(xs[j], -clampv), clampv);
    int X = (int)rintf(xv * scale);
    int d0 = (int)(s8)(X & 255); X = (X - d0) >> 8;
    int d1 = (int)(s8)(X & 255); X = (X - d1) >> 8;
    int d2 = (int)(s8)(X & 255); X = (X - d2) >> 8;
    int d3 = X;
    p0 |= ((u64)(u8)(s8)d0) << (8*j);
    p1 |= ((u64)(u8)(s8)d1) << (8*j);
    p2 |= ((u64)(u8)(s8)d2) << (8*j);
    p3 |= ((u64)(u8)(s8)d3) << (8*j);
  }
  u64* o = (u64*)dig;
  size_t np8 = (size_t)n8;
  o[t] = p0; o[np8 + t] = p1; o[2*np8 + t] = p2; o[3*np8 + t] = p3;
}

// ---------------------------------------------------------------------------
// Precise GEMM via exact fixed-point i8 MFMA. Epilogue writes:
//   Cd: exact double, Cb: bf16 hi, Cl: bf16 lo residual.
// ---------------------------------------------------------------------------
#define MFMA_I8(c, a, b) asm volatile("v_mfma_i32_16x16x64_i8 %0, %1, %2, %0" : "+v"(c) : "v"(a), "v"(b))

__global__ __launch_bounds__(256) void gemm_i8(
    const s8* __restrict__ Ad, const s8* __restrict__ Wd, const float* __restrict__ bias,
    double* __restrict__ Cd, u16* __restrict__ Cb, u16* __restrict__ Cl)
{
  __shared__ alignas(16) s8 As[4][32][80];
  __shared__ alignas(16) s8 Bs[4][32][80];
  const int i0 = blockIdx.x * 32, o0 = blockIdx.y * 32;
  const int t = threadIdx.x, w = t >> 6, lane = t & 63;
  const int wr = w >> 1, wc = w & 1, l15 = lane & 15, lg = lane >> 4;
  const size_t APL = 4194304, WPL = 1048576;

  v4i c0={0,0,0,0}, c1={0,0,0,0}, c2={0,0,0,0}, c3={0,0,0,0}, c4={0,0,0,0};

  for (int kt = 0; kt < 16; ++kt){
#pragma unroll
    for (int j = 0; j < 2; ++j){
      int cid = t*2 + j;
      int p = cid >> 7, rem = cid & 127;
      int row = rem >> 2, c16 = (rem & 3) << 4;
      int4 av = *(const int4*)(Ad + (size_t)p*APL + (size_t)(i0+row)*1024 + kt*64 + c16);
      *(int4*)&As[p][row][c16] = av;
      int4 bv = *(const int4*)(Wd + (size_t)p*WPL + (size_t)(o0+row)*1024 + kt*64 + c16);
      *(int4*)&Bs[p][row][c16] = bv;
    }
    __syncthreads();
    v4i a0 = *(const v4i*)&As[0][wr*16+l15][lg*16];
    v4i a1 = *(const v4i*)&As[1][wr*16+l15][lg*16];
    v4i a2 = *(const v4i*)&As[2][wr*16+l15][lg*16];
    v4i a3 = *(const v4i*)&As[3][wr*16+l15][lg*16];
    v4i b0 = *(const v4i*)&Bs[0][wc*16+l15][lg*16];
    v4i b1 = *(const v4i*)&Bs[1][wc*16+l15][lg*16];
    v4i b2 = *(const v4i*)&Bs[2][wc*16+l15][lg*16];
    v4i b3 = *(const v4i*)&Bs[3][wc*16+l15][lg*16];
    MFMA_I8(c0, a0, b2); MFMA_I8(c0, a1, b1); MFMA_I8(c0, a2, b0);
    MFMA_I8(c1, a0, b3); MFMA_I8(c1, a1, b2); MFMA_I8(c1, a2, b1); MFMA_I8(c1, a3, b0);
    MFMA_I8(c2, a1, b3); MFMA_I8(c2, a2, b2); MFMA_I8(c2, a3, b1);
    MFMA_I8(c3, a2, b3); MFMA_I8(c3, a3, b2);
    MFMA_I8(c4, a3, b3);
    __syncthreads();
  }
  const int oc = o0 + wc*16 + l15;
  const double bv = (double)bias[oc];
#pragma unroll
  for (int e = 0; e < 4; ++e){
    double val = (double)c0[e]*0x1p-43 + (double)c1[e]*0x1p-35 + (double)c2[e]*0x1p-27
               + (double)c3[e]*0x1p-19 + (double)c4[e]*0x1p-11 + bv;
    int orow = i0 + wr*16 + lg*4 + e;
    size_t idx = (size_t)orow*1024 + oc;
    Cd[idx] = val;
    float hi = (float)val;
    u16 hb = f2bf(hi);
    float lof = (float)(val - (double)bf2f(hb));
    Cb[idx] = hb;
    Cl[idx] = f2bf(lof);
  }
}

// ---------------------------------------------------------------------------
// bf16 GEMM (A fp32->bf16 or A bf16), out fp32 or bf16.
// ---------------------------------------------------------------------------
template<int ABF16, int OUTBF>
__global__ __launch_bounds__(256) void gemm_bf16k(
    const void* __restrict__ Ap, const float* __restrict__ W, const float* __restrict__ bias,
    void* __restrict__ C)
{
  __shared__ alignas(16) u16 As[32][72];
  __shared__ alignas(16) u16 Bs[32][72];
  const int i0 = blockIdx.x * 32, o0 = blockIdx.y * 32;
  const int t = threadIdx.x, w = t >> 6, lane = t & 63;
  const int wr = w >> 1, wc = w & 1, l15 = lane & 15, lg = lane >> 4;
  const int row = t >> 3, c8 = (t & 7) * 8;
  v4f acc = {0.f,0.f,0.f,0.f};
  for (int kt = 0; kt < 16; ++kt){
    if (ABF16){
      v8s x = *(const v8s*)((const u16*)Ap + (size_t)(i0+row)*1024 + kt*64 + c8);
      *(v8s*)&As[row][c8] = x;
    } else {
      const float* A = (const float*)Ap;
      const float4 x0 = *(const float4*)(A + (size_t)(i0+row)*1024 + kt*64 + c8);
      const float4 x1 = *(const float4*)(A + (size_t)(i0+row)*1024 + kt*64 + c8 + 4);
      v8s pk;
      pk[0]=(short)f2bf(x0.x); pk[1]=(short)f2bf(x0.y); pk[2]=(short)f2bf(x0.z); pk[3]=(short)f2bf(x0.w);
      pk[4]=(short)f2bf(x1.x); pk[5]=(short)f2bf(x1.y); pk[6]=(short)f2bf(x1.z); pk[7]=(short)f2bf(x1.w);
      *(v8s*)&As[row][c8] = pk;
    }
    {
      const float4 y0 = *(const float4*)(W + (size_t)(o0+row)*1024 + kt*64 + c8);
      const float4 y1 = *(const float4*)(W + (size_t)(o0+row)*1024 + kt*64 + c8 + 4);
      v8s pk;
      pk[0]=(short)f2bf(y0.x); pk[1]=(short)f2bf(y0.y); pk[2]=(short)f2bf(y0.z); pk[3]=(short)f2bf(y0.w);
      pk[4]=(short)f2bf(y1.x); pk[5]=(short)f2bf(y1.y); pk[6]=(short)f2bf(y1.z); pk[7]=(short)f2bf(y1.w);
      *(v8s*)&Bs[row][c8] = pk;
    }
    __syncthreads();
    v8s a0 = *(const v8s*)&As[wr*16+l15][lg*8];
    v8s a1 = *(const v8s*)&As[wr*16+l15][lg*8+32];
    v8s b0 = *(const v8s*)&Bs[wc*16+l15][lg*8];
    v8s b1 = *(const v8s*)&Bs[wc*16+l15][lg*8+32];
    acc = __builtin_amdgcn_mfma_f32_16x16x32_bf16(a0, b0, acc, 0, 0, 0);
    acc = __builtin_amdgcn_mfma_f32_16x16x32_bf16(a1, b1, acc, 0, 0, 0);
    __syncthreads();
  }
  const int oc = o0 + wc*16 + l15;
  const float bvv = bias[oc];
#pragma unroll
  for (int e=0;e<4;e++){
    int orow = i0 + wr*16 + lg*4 + e;
    size_t idx = (size_t)orow*1024 + oc;
    if (OUTBF) ((u16*)C)[idx] = f2bf(acc[e] + bvv);
    else       ((float*)C)[idx] = acc[e] + bvv;
  }
}

// ---------------------------------------------------------------------------
// Fused top-k attention, round 5:
//  - NO LDS score matrix: prefilter fused into phase 1 (in-register, per-wave
//    slice), candidates compacted into per-(row,wave) LDS segments (cap 48)
//  - 32 q-rows/WG (halves K L2 re-reads); owner waves process 4 rows
//    interleaved (4x ILP on binsearch/rescore/rank/softmax/PV chains)
//  - PV: 2 dims x 2 sels per lane, uniform-LDS prob broadcast
//  - guarantees as R4 (T0=1.5, t64>=1.5125 check, delta-band, fp64 ranking);
//    overflow/guarantee failures -> exact-fp64 per-wave fallback (~never)
// ---------------------------------------------------------------------------
__global__ __launch_bounds__(512, 4) void attn_topk(
    const u16* __restrict__ Qb, const u16* __restrict__ Kb,
    const u16* __restrict__ Ql, const u16* __restrict__ Kl,
    const double* __restrict__ Qd, const double* __restrict__ Kd,
    const u16* __restrict__ Vb, u16* __restrict__ Ab)
{
  __shared__ u32 stageL[32*8*48];   // 48 KB candidate segments
  __shared__ u64 selpL[32*64];      // 16 KB (idx, score/prob) pairs
  __shared__ u32 cntL[32*8];        // 1 KB
  __shared__ u32 flagL[32];         // 128 B

  const int lid = blockIdx.y * 64 + blockIdx.x;
  const int bh  = (lid & 7) * 4 + (lid >> 9);
  const int qb  = (lid >> 3) & 63;
  const size_t base = (size_t)(bh >> 4) * 2097152 + (size_t)(bh & 15) * 131072;
  const int q0 = qb * 32;
  const int tid = threadIdx.x, w = tid >> 6, lane = tid & 63;
  const int l15 = lane & 15, lg = lane >> 4;
  const u64 ltmask = (1ull << lane) - 1ull;

  if (tid < 32) flagL[tid] = 0u;
  __syncthreads();

  // ---- Phase 1: MFMA scores + fused prefilter (T0 = 1.5) ----
  const v4f vzero = {0.f,0.f,0.f,0.f};
  for (int bi = 0; bi < 2; ++bi){
    const int rbase = bi * 16;
    const size_t qoff = base + (size_t)(q0 + rbase + l15)*64 + lg*8;
    v8s a0  = *(const v8s*)(Qb + qoff);
    v8s a1  = *(const v8s*)(Qb + qoff + 32);
    v8s a0l = *(const v8s*)(Ql + qoff);
    v8s a1l = *(const v8s*)(Ql + qoff + 32);
    int cnt[4] = {0,0,0,0};
#pragma unroll 2
    for (int kt = 0; kt < 16; ++kt){
      int kk0 = w*256 + kt*16;
      const size_t koff = base + (size_t)(kk0 + l15)*64 + lg*8;
      v8s b0  = *(const v8s*)(Kb + koff);
      v8s b1  = *(const v8s*)(Kb + koff + 32);
      v8s b0l = *(const v8s*)(Kl + koff);
      v8s b1l = *(const v8s*)(Kl + koff + 32);
      v4f hh = __builtin_amdgcn_mfma_f32_16x16x32_bf16(a0,  b0,  vzero, 0, 0, 0);
      v4f hl = __builtin_amdgcn_mfma_f32_16x16x32_bf16(a0,  b0l, vzero, 0, 0, 0);
      v4f lh = __builtin_amdgcn_mfma_f32_16x16x32_bf16(a0l, b0,  vzero, 0, 0, 0);
      hh = __builtin_amdgcn_mfma_f32_16x16x32_bf16(a1,  b1,  hh, 0, 0, 0);
      hl = __builtin_amdgcn_mfma_f32_16x16x32_bf16(a1,  b1l, hl, 0, 0, 0);
      lh = __builtin_amdgcn_mfma_f32_16x16x32_bf16(a1l, b1,  lh, 0, 0, 0);
#pragma unroll
      for (int e = 0; e < 4; ++e){
        float sc = ((hh[e] + hl[e]) + lh[e]) * 0.125f;
        bool hit = sc >= 1.5f;
        u64 mk = __ballot(hit);
        u32 nib = (u32)(mk >> (lg*16)) & 0xFFFFu;
        int pos = cnt[e] + (int)__popc(nib & ((1u << l15) - 1u));
        if (hit && pos < 48)
          stageL[(u32)((rbase + lg*4 + e)*8 + w)*48u + (u32)pos] =
              ((u32)f2bf(sc) << 16) | (u32)(kk0 + l15);
        cnt[e] += (int)__popc(nib);
      }
    }
    if (l15 == 0){
#pragma unroll
      for (int e = 0; e < 4; ++e){
        int row = rbase + lg*4 + e;
        cntL[row*8 + w] = (u32)cnt[e];
        if (cnt[e] > 48) flagL[row] = 1u;
      }
    }
  }
  __syncthreads();   // only block-wide barrier after init

  // ---- Phase 2: owner wave w handles rows R0..R0+3 (interleaved) ----
  const int R0 = w * 4;
  u32 pk0[4], pk1[4], pk2[4], cstore[4], tv[4];
  bool fail[4];

#pragma unroll
  for (int rr = 0; rr < 4; ++rr){
    const int R = R0 + rr;
    uint4 ca = *(const uint4*)&cntL[R*8];
    uint4 cb = *(const uint4*)&cntL[R*8 + 4];
    u32 P1 = ca.x, P2 = P1+ca.y, P3 = P2+ca.z, P4 = P3+ca.w;
    u32 P5 = P4+cb.x, P6 = P5+cb.y, P7 = P6+cb.z;
    cstore[rr] = P7 + cb.w;
    fail[rr] = (flagL[R] != 0u) || (cstore[rr] > 192u);
#pragma unroll
    for (int s = 0; s < 3; ++s){
      u32 idx = (u32)(64*s + lane);
      u32 pb = 0, wsel = 0;
      if (idx >= P1){ pb = P1; wsel = 1; }
      if (idx >= P2){ pb = P2; wsel = 2; }
      if (idx >= P3){ pb = P3; wsel = 3; }
      if (idx >= P4){ pb = P4; wsel = 4; }
      if (idx >= P5){ pb = P5; wsel = 5; }
      if (idx >= P6){ pb = P6; wsel = 6; }
      if (idx >= P7){ pb = P7; wsel = 7; }
      u32 off = idx - pb; off = off > 47u ? 47u : off;
      u32 val = stageL[(u32)(R*8 + (int)wsel)*48u + off];
      val = (idx < cstore[rr]) ? val : 0u;
      if (s == 0) pk0[rr] = val; else if (s == 1) pk1[rr] = val; else pk2[rr] = val;
    }
    tv[rr] = 0u;
  }

  // exact bf16-64th via ballot binsearch (4 rows interleaved)
  for (int bit = 14; bit >= 0; --bit){
#pragma unroll
    for (int rr = 0; rr < 4; ++rr){
      u32 tt = tv[rr] | (1u << bit);
      int c = (int)__popcll(__ballot((pk0[rr] >> 16) >= tt))
            + (int)__popcll(__ballot((pk1[rr] >> 16) >= tt))
            + (int)__popcll(__ballot((pk2[rr] >> 16) >= tt));
      if (c >= 64) tv[rr] = tt;
    }
  }

  // classify into auto / band
  int na[4], nb[4];
#pragma unroll
  for (int rr = 0; rr < 4; ++rr){
    const int R = R0 + rr;
    float t64f = bf2f((u16)tv[rr]);
    bool fl = fail[rr] || (t64f < 1.5125f);
    fail[rr] = fl;
    float thi = t64f + 0.012f, tlo = t64f - 0.012f;
    int a_ = 0, b_ = 0;
#pragma unroll
    for (int s = 0; s < 3; ++s){
      u32 pkv = (s == 0) ? pk0[rr] : ((s == 1) ? pk1[rr] : pk2[rr]);
      bool act = (u32)(64*s + lane) < cstore[rr];
      float v = bf2f((u16)(pkv >> 16));
      bool aut = act && (v > thi);
      bool ban = act && !aut && (v >= tlo);
      u64 ma = __ballot(aut);
      if (aut && !fl){
        int pos = a_ + (int)__popcll(ma & ltmask);
        if (pos < 64) selpL[R*64 + pos] = ((u64)(pkv & 0xFFFF0000u) << 32) | (u64)(pkv & 0x7FFu);
      }
      a_ += (int)__popcll(ma);
      u64 mb = __ballot(ban);
      if (ban && !fl){
        int pos = b_ + (int)__popcll(mb & ltmask);
        if (pos < 64) stageL[(u32)(R*8)*48u + (u32)pos] = pkv;   // scratch (row's own stage)
      }
      b_ += (int)__popcll(mb);
    }
    na[rr] = fl ? 64 : (a_ > 64 ? 64 : a_);
    nb[rr] = fl ? 0  : (b_ > 64 ? 64 : b_);
  }
  asm volatile("s_waitcnt lgkmcnt(0)" ::: "memory");
  __builtin_amdgcn_sched_barrier(0);

  // fp64 rescore of band (candidate-per-lane, 4 rows interleaved)
  const double* Kdh = Kd + base;
  const double* Qdh = Qd + base + (size_t)q0*64;
  u32 bpk[4];
#pragma unroll
  for (int rr = 0; rr < 4; ++rr)
    bpk[rr] = (lane < nb[rr]) ? stageL[(u32)((R0+rr)*8)*48u + (u32)lane] : 0u;
  double ac0[4] = {0,0,0,0}, ac1[4] = {0,0,0,0};
#pragma unroll 4
  for (int j = 0; j < 32; ++j){
#pragma unroll
    for (int rr = 0; rr < 4; ++rr){
      double2 kv = ((const double2*)(Kdh + (size_t)(bpk[rr] & 0x7FFu)*64))[j];
      double2 qv = ((const double2*)(Qdh + (size_t)(R0+rr)*64))[j];
      ac0[rr] = fma(qv.x, kv.x, ac0[rr]);
      ac1[rr] = fma(qv.y, kv.y, ac1[rr]);
    }
  }
  double mv[4]; int mi[4];
#pragma unroll
  for (int rr = 0; rr < 4; ++rr){
    mv[rr] = (lane < nb[rr]) ? (ac0[rr] + ac1[rr]) : -1.0e300;
    mi[rr] = (lane < nb[rr]) ? (int)(bpk[rr] & 0x7FFu) : 0x7FFFFFFF;
  }
  int maxnb = nb[0];
  if (nb[1] > maxnb) maxnb = nb[1];
  if (nb[2] > maxnb) maxnb = nb[2];
  if (nb[3] > maxnb) maxnb = nb[3];
  int rank[4] = {0,0,0,0};
  for (int j = 0; j < maxnb; ++j){
#pragma unroll
    for (int rr = 0; rr < 4; ++rr){
      double ov = __shfl(mv[rr], j); int oi = __shfl(mi[rr], j);
      rank[rr] += (ov > mv[rr] || (ov == mv[rr] && oi < mi[rr])) ? 1 : 0;
    }
  }
#pragma unroll
  for (int rr = 0; rr < 4; ++rr){
    int need = 64 - na[rr]; if (need > nb[rr]) need = nb[rr];
    if (lane < nb[rr] && rank[rr] < need)
      selpL[(R0+rr)*64 + na[rr] + rank[rr]] =
          ((u64)(bpk[rr] & 0xFFFF0000u) << 32) | (u64)(bpk[rr] & 0x7FFu);
  }

  // fallback (exact fp64, wave-uniform, ~never taken)
#pragma unroll
  for (int rr = 0; rr < 4; ++rr){
    if (__builtin_expect(fail[rr], 0)){
      const int R = R0 + rr;
      const double* Qrow = Qdh + (size_t)R*64;
      float vals[32];
#pragma unroll
      for (int m = 0; m < 32; ++m){
        const double2* Kr = (const double2*)(Kdh + ((size_t)lane*32 + m)*64);
        double s0 = 0.0, s1 = 0.0;
        for (int j = 0; j < 32; ++j){
          double2 kv = Kr[j];
          double2 qv = ((const double2*)Qrow)[j];
          s0 = fma(qv.x, kv.x, s0);
          s1 = fma(qv.y, kv.y, s1);
        }
        vals[m] = (float)((s0 + s1) * 0.125);
      }
      float pvv = 3.4e38f; int pii = -1;
      for (int step = 0; step < 64; ++step){
        float bv = -3.4e38f; int bi2 = 0x7FFFFFFF;
#pragma unroll
        for (int m = 0; m < 32; ++m){
          int col = lane*32 + m;
          bool after = (vals[m] < pvv) || (vals[m] == pvv && col > pii);
          bool bet = after && (vals[m] > bv || (vals[m] == bv && col < bi2));
          bv  = bet ? vals[m] : bv;
          bi2 = bet ? col : bi2;
        }
#pragma unroll
        for (int off = 32; off; off >>= 1){
          float ovv = __shfl_xor(bv, off); int oii = __shfl_xor(bi2, off);
          bool tk = (ovv > bv) || (ovv == bv && oii < bi2);
          bv = tk ? ovv : bv; bi2 = tk ? oii : bi2;
        }
        if (lane == 0)
          selpL[R*64 + step] = ((u64)__builtin_bit_cast(u32, bv) << 32) | (u64)(u32)bi2;
        pvv = bv; pii = bi2;
      }
    }
  }
  asm volatile("s_waitcnt lgkmcnt(0)" ::: "memory");
  __builtin_amdgcn_sched_barrier(0);

  // softmax over the 64 selected (4 rows interleaved)
  u32 sidx[4]; float scv[4], pp[4];
#pragma unroll
  for (int rr = 0; rr < 4; ++rr){
    u64 pr = selpL[(R0+rr)*64 + lane];
    sidx[rr] = (u32)pr & 0x7FFu;
    scv[rr] = __builtin_bit_cast(float, (u32)(pr >> 32));
  }
#pragma unroll
  for (int rr = 0; rr < 4; ++rr){
    float mx = scv[rr];
#pragma unroll
    for (int off = 32; off; off >>= 1) mx = fmaxf(mx, __shfl_xor(mx, off));
    float p = expf(scv[rr] - mx);
    float Z = p;
#pragma unroll
    for (int off = 32; off; off >>= 1) Z += __shfl_xor(Z, off);
    pp[rr] = p / Z;
  }
#pragma unroll
  for (int rr = 0; rr < 4; ++rr)
    selpL[(R0+rr)*64 + lane] = ((u64)__builtin_bit_cast(u32, pp[rr]) << 32) | (u64)sidx[rr];
  asm volatile("s_waitcnt lgkmcnt(0)" ::: "memory");
  __builtin_amdgcn_sched_barrier(0);

  // PV: 2 dims x 2 sels per lane, uniform-LDS broadcasts (4 rows interleaved)
  const int h = lane >> 5, dl = lane & 31;
  float u0[4] = {0,0,0,0}, u1[4] = {0,0,0,0};
#pragma unroll 2
  for (int j = 0; j < 64; j += 2){
#pragma unroll
    for (int rr = 0; rr < 4; ++rr){
      u64 pr = selpL[(R0+rr)*64 + j + h];
      float pv = __builtin_bit_cast(float, (u32)(pr >> 32));
      u32 vv = *(const u32*)(Vb + base + (size_t)((u32)pr & 0x7FFu)*64 + 2*dl);
      u0[rr] = fmaf(pv, bf2f((u16)(vv & 0xFFFFu)), u0[rr]);
      u1[rr] = fmaf(pv, bf2f((u16)(vv >> 16)),     u1[rr]);
    }
  }
#pragma unroll
  for (int rr = 0; rr < 4; ++rr){
    u0[rr] += __shfl_xor(u0[rr], 32);
    u1[rr] += __shfl_xor(u1[rr], 32);
  }
  if (lane < 32){
#pragma unroll
    for (int rr = 0; rr < 4; ++rr){
      u32 o = (u32)f2bf(u0[rr]) | ((u32)f2bf(u1[rr]) << 16);
      *(u32*)(Ab + base + (size_t)(q0 + R0 + rr)*64 + 2*dl) = o;
    }
  }
}

// ---------------------------------------------------------------------------
extern "C" void kernel_launch(void* const* d_in, const int* in_sizes, int n_in,
                              void* d_out, int out_size, void* d_ws, size_t ws_size,
                              hipStream_t stream)
{
  (void)in_sizes; (void)n_in; (void)out_size; (void)ws_size;
  const float* q  = (const float*)d_in[0];
  const float* k  = (const float*)d_in[1];
  const float* v  = (const float*)d_in[2];
  const float* Wq = (const float*)d_in[3];
  const float* bq = (const float*)d_in[4];
  const float* Wk = (const float*)d_in[5];
  const float* bk = (const float*)d_in[6];
  const float* Wv = (const float*)d_in[7];
  const float* bv = (const float*)d_in[8];
  const float* Wo = (const float*)d_in[9];
  const float* bo = (const float*)d_in[10];

  char* ws = (char*)d_ws;
  const size_t MB = 1048576;
  double* Qd  = (double*)(ws);             // 32 MB
  double* Kd  = (double*)(ws + 32*MB);     // 32 MB
  u16*    Qb  = (u16*)  (ws + 64*MB);      // 8 MB  (hi)
  u16*    Kb  = (u16*)  (ws + 72*MB);      // 8 MB  (hi)
  u16*    Ql  = (u16*)  (ws + 80*MB);      // 8 MB  (lo)
  u16*    Kl  = (u16*)  (ws + 88*MB);      // 8 MB  (lo)
  u16*    Abf = (u16*)  (ws + 96*MB);      // 8 MB
  s8*     dact= (s8*)   (ws + 104*MB);     // 16 MB (dead after K-proj)
  u16*    Vbf = (u16*)  (ws + 104*MB);     // 8 MB  (aliases dact, written after)
  s8*     dw  = (s8*)   (ws + 120*MB);     // 4 MB  -> total 124 MB

  quant_digits<<<2048, 256, 0, stream>>>(q,  dact, 4194304, 134217728.0f, 7.75f);    // 2^27
  quant_digits<<<512,  256, 0, stream>>>(Wq, dw,   1048576, 4294967296.0f, 0.2495f); // 2^32
  gemm_i8<<<dim3(128, 32), 256, 0, stream>>>(dact, dw, bq, Qd, Qb, Ql);
  quant_digits<<<2048, 256, 0, stream>>>(k,  dact, 4194304, 134217728.0f, 7.75f);
  quant_digits<<<512,  256, 0, stream>>>(Wk, dw,   1048576, 4294967296.0f, 0.2495f);
  gemm_i8<<<dim3(128, 32), 256, 0, stream>>>(dact, dw, bk, Kd, Kb, Kl);
  gemm_bf16k<0,1><<<dim3(128, 32), 256, 0, stream>>>(v, Wv, bv, Vbf);
  attn_topk<<<dim3(64, 32), 512, 0, stream>>>(Qb, Kb, Ql, Kl, Qd, Kd, Vbf, Abf);
  gemm_bf16k<1,0><<<dim3(128, 32), 256, 0, stream>>>(Abf, Wo, bo, d_out);
}

// Round 7
// 671.574 us; speedup vs baseline: 5.8873x; 5.8873x over previous
//
#include <hip/hip_runtime.h>
#include <stdint.h>

using u8  = unsigned char;
using s8  = signed char;
using u16 = unsigned short;
using u32 = unsigned int;
using u64 = unsigned long long;

typedef int   v4i __attribute__((ext_vector_type(4)));
typedef float v4f __attribute__((ext_vector_type(4)));
typedef short v8s __attribute__((ext_vector_type(8)));

__device__ __forceinline__ u16 f2bf(float f){
  u32 u = __builtin_bit_cast(u32, f);
  u32 r = (u + 0x7FFFu + ((u >> 16) & 1u)) >> 16;
  return (u16)r;
}
__device__ __forceinline__ float bf2f(u16 b){
  u32 u = ((u32)b) << 16;
  return __builtin_bit_cast(float, u);
}

// ---------------------------------------------------------------------------
// Quantize fp32 -> 4 signed-i8 digit planes of X = rint(x*scale). Exact.
// ---------------------------------------------------------------------------
__global__ __launch_bounds__(256) void quant_digits(
    const float* __restrict__ in, s8* __restrict__ dig, int n, float scale, float clampv)
{
  int t = blockIdx.x * 256 + threadIdx.x;
  int n8 = n >> 3;
  if (t >= n8) return;
  const float4* inv = (const float4*)in;
  float4 a = inv[2*t], b = inv[2*t+1];
  float xs[8] = {a.x,a.y,a.z,a.w,b.x,b.y,b.z,b.w};
  u64 p0=0,p1=0,p2=0,p3=0;
#pragma unroll
  for (int j=0;j<8;j++){
    float xv = fminf(fmaxf(xs[j], -clampv), clampv);
    int X = (int)rintf(xv * scale);
    int d0 = (int)(s8)(X & 255); X = (X - d0) >> 8;
    int d1 = (int)(s8)(X & 255); X = (X - d1) >> 8;
    int d2 = (int)(s8)(X & 255); X = (X - d2) >> 8;
    int d3 = X;
    p0 |= ((u64)(u8)(s8)d0) << (8*j);
    p1 |= ((u64)(u8)(s8)d1) << (8*j);
    p2 |= ((u64)(u8)(s8)d2) << (8*j);
    p3 |= ((u64)(u8)(s8)d3) << (8*j);
  }
  u64* o = (u64*)dig;
  size_t np8 = (size_t)n8;
  o[t] = p0; o[np8 + t] = p1; o[2*np8 + t] = p2; o[3*np8 + t] = p3;
}

// ---------------------------------------------------------------------------
// Precise GEMM via exact fixed-point i8 MFMA. Epilogue writes:
//   Cd: exact double, Cb: bf16 hi, Cl: bf16 lo residual.
// ---------------------------------------------------------------------------
#define MFMA_I8(c, a, b) asm volatile("v_mfma_i32_16x16x64_i8 %0, %1, %2, %0" : "+v"(c) : "v"(a), "v"(b))

__global__ __launch_bounds__(256) void gemm_i8(
    const s8* __restrict__ Ad, const s8* __restrict__ Wd, const float* __restrict__ bias,
    double* __restrict__ Cd, u16* __restrict__ Cb, u16* __restrict__ Cl)
{
  __shared__ alignas(16) s8 As[4][32][80];
  __shared__ alignas(16) s8 Bs[4][32][80];
  const int i0 = blockIdx.x * 32, o0 = blockIdx.y * 32;
  const int t = threadIdx.x, w = t >> 6, lane = t & 63;
  const int wr = w >> 1, wc = w & 1, l15 = lane & 15, lg = lane >> 4;
  const size_t APL = 4194304, WPL = 1048576;

  v4i c0={0,0,0,0}, c1={0,0,0,0}, c2={0,0,0,0}, c3={0,0,0,0}, c4={0,0,0,0};

  for (int kt = 0; kt < 16; ++kt){
#pragma unroll
    for (int j = 0; j < 2; ++j){
      int cid = t*2 + j;
      int p = cid >> 7, rem = cid & 127;
      int row = rem >> 2, c16 = (rem & 3) << 4;
      int4 av = *(const int4*)(Ad + (size_t)p*APL + (size_t)(i0+row)*1024 + kt*64 + c16);
      *(int4*)&As[p][row][c16] = av;
      int4 bv = *(const int4*)(Wd + (size_t)p*WPL + (size_t)(o0+row)*1024 + kt*64 + c16);
      *(int4*)&Bs[p][row][c16] = bv;
    }
    __syncthreads();
    v4i a0 = *(const v4i*)&As[0][wr*16+l15][lg*16];
    v4i a1 = *(const v4i*)&As[1][wr*16+l15][lg*16];
    v4i a2 = *(const v4i*)&As[2][wr*16+l15][lg*16];
    v4i a3 = *(const v4i*)&As[3][wr*16+l15][lg*16];
    v4i b0 = *(const v4i*)&Bs[0][wc*16+l15][lg*16];
    v4i b1 = *(const v4i*)&Bs[1][wc*16+l15][lg*16];
    v4i b2 = *(const v4i*)&Bs[2][wc*16+l15][lg*16];
    v4i b3 = *(const v4i*)&Bs[3][wc*16+l15][lg*16];
    MFMA_I8(c0, a0, b2); MFMA_I8(c0, a1, b1); MFMA_I8(c0, a2, b0);
    MFMA_I8(c1, a0, b3); MFMA_I8(c1, a1, b2); MFMA_I8(c1, a2, b1); MFMA_I8(c1, a3, b0);
    MFMA_I8(c2, a1, b3); MFMA_I8(c2, a2, b2); MFMA_I8(c2, a3, b1);
    MFMA_I8(c3, a2, b3); MFMA_I8(c3, a3, b2);
    MFMA_I8(c4, a3, b3);
    __syncthreads();
  }
  const int oc = o0 + wc*16 + l15;
  const double bv = (double)bias[oc];
#pragma unroll
  for (int e = 0; e < 4; ++e){
    double val = (double)c0[e]*0x1p-43 + (double)c1[e]*0x1p-35 + (double)c2[e]*0x1p-27
               + (double)c3[e]*0x1p-19 + (double)c4[e]*0x1p-11 + bv;
    int orow = i0 + wr*16 + lg*4 + e;
    size_t idx = (size_t)orow*1024 + oc;
    Cd[idx] = val;
    float hi = (float)val;
    u16 hb = f2bf(hi);
    float lof = (float)(val - (double)bf2f(hb));
    Cb[idx] = hb;
    Cl[idx] = f2bf(lof);
  }
}

// ---------------------------------------------------------------------------
// bf16 GEMM (A fp32->bf16 or A bf16), out fp32 or bf16.
// ---------------------------------------------------------------------------
template<int ABF16, int OUTBF>
__global__ __launch_bounds__(256) void gemm_bf16k(
    const void* __restrict__ Ap, const float* __restrict__ W, const float* __restrict__ bias,
    void* __restrict__ C)
{
  __shared__ alignas(16) u16 As[32][72];
  __shared__ alignas(16) u16 Bs[32][72];
  const int i0 = blockIdx.x * 32, o0 = blockIdx.y * 32;
  const int t = threadIdx.x, w = t >> 6, lane = t & 63;
  const int wr = w >> 1, wc = w & 1, l15 = lane & 15, lg = lane >> 4;
  const int row = t >> 3, c8 = (t & 7) * 8;
  v4f acc = {0.f,0.f,0.f,0.f};
  for (int kt = 0; kt < 16; ++kt){
    if (ABF16){
      v8s x = *(const v8s*)((const u16*)Ap + (size_t)(i0+row)*1024 + kt*64 + c8);
      *(v8s*)&As[row][c8] = x;
    } else {
      const float* A = (const float*)Ap;
      const float4 x0 = *(const float4*)(A + (size_t)(i0+row)*1024 + kt*64 + c8);
      const float4 x1 = *(const float4*)(A + (size_t)(i0+row)*1024 + kt*64 + c8 + 4);
      v8s pk;
      pk[0]=(short)f2bf(x0.x); pk[1]=(short)f2bf(x0.y); pk[2]=(short)f2bf(x0.z); pk[3]=(short)f2bf(x0.w);
      pk[4]=(short)f2bf(x1.x); pk[5]=(short)f2bf(x1.y); pk[6]=(short)f2bf(x1.z); pk[7]=(short)f2bf(x1.w);
      *(v8s*)&As[row][c8] = pk;
    }
    {
      const float4 y0 = *(const float4*)(W + (size_t)(o0+row)*1024 + kt*64 + c8);
      const float4 y1 = *(const float4*)(W + (size_t)(o0+row)*1024 + kt*64 + c8 + 4);
      v8s pk;
      pk[0]=(short)f2bf(y0.x); pk[1]=(short)f2bf(y0.y); pk[2]=(short)f2bf(y0.z); pk[3]=(short)f2bf(y0.w);
      pk[4]=(short)f2bf(y1.x); pk[5]=(short)f2bf(y1.y); pk[6]=(short)f2bf(y1.z); pk[7]=(short)f2bf(y1.w);
      *(v8s*)&Bs[row][c8] = pk;
    }
    __syncthreads();
    v8s a0 = *(const v8s*)&As[wr*16+l15][lg*8];
    v8s a1 = *(const v8s*)&As[wr*16+l15][lg*8+32];
    v8s b0 = *(const v8s*)&Bs[wc*16+l15][lg*8];
    v8s b1 = *(const v8s*)&Bs[wc*16+l15][lg*8+32];
    acc = __builtin_amdgcn_mfma_f32_16x16x32_bf16(a0, b0, acc, 0, 0, 0);
    acc = __builtin_amdgcn_mfma_f32_16x16x32_bf16(a1, b1, acc, 0, 0, 0);
    __syncthreads();
  }
  const int oc = o0 + wc*16 + l15;
  const float bvv = bias[oc];
#pragma unroll
  for (int e=0;e<4;e++){
    int orow = i0 + wr*16 + lg*4 + e;
    size_t idx = (size_t)orow*1024 + oc;
    if (OUTBF) ((u16*)C)[idx] = f2bf(acc[e] + bvv);
    else       ((float*)C)[idx] = acc[e] + bvv;
  }
}

// ---------------------------------------------------------------------------
// Fused top-k attention, round 7:
//  - ROW-ADAPTIVE prefilter T0 = 1.5*|Q_row|/8 (fixes the 5%-flag-rate bug:
//    per-row score std = |Q|/8, not 1) -> flag rate ~0.4%
//  - corrected margins for bf16 half-step at scores in [2,4): delta=0.0105,
//    band +-0.021, guarantee check t64f >= T0+0.025, flag if t64f >= 4
//  - fallback kernel covers ALL rows (grid 4096) and uses LDS vals
// ---------------------------------------------------------------------------
__global__ __launch_bounds__(512, 4) void attn_topk(
    const u16* __restrict__ Qb, const u16* __restrict__ Kb,
    const u16* __restrict__ Ql, const u16* __restrict__ Kl,
    const double* __restrict__ Qd, const double* __restrict__ Kd,
    const u16* __restrict__ Vb, u16* __restrict__ Ab, u32* __restrict__ flags)
{
  __shared__ u32 stageL[16*8*48];   // 24 KB candidate segments
  __shared__ u64 selpL[16*64];      // 8 KB (score/prob, idx) pairs
  __shared__ u32 cntL[16*8];        // 512 B
  __shared__ u32 flagL[16];

  const int lid = blockIdx.y * 128 + blockIdx.x;
  const int bh  = (lid & 7) * 4 + (lid >> 10);
  const int qb  = (lid >> 3) & 127;
  const size_t base = (size_t)(bh >> 4) * 2097152 + (size_t)(bh & 15) * 131072;
  const int q0 = qb * 16;
  const int tid = threadIdx.x, w = tid >> 6, lane = tid & 63;
  const int l15 = lane & 15, lg = lane >> 4;
  const u64 ltmask = (1ull << lane) - 1ull;

  if (tid < 16) flagL[tid] = 0u;
  __syncthreads();

  // ---- Phase 1: MFMA scores + fused row-adaptive prefilter ----
  const v4f vzero = {0.f,0.f,0.f,0.f};
  float nrm2;
  {
    const size_t qoff = base + (size_t)(q0 + l15)*64 + lg*8;
    v8s a0  = *(const v8s*)(Qb + qoff);
    v8s a1  = *(const v8s*)(Qb + qoff + 32);
    v8s a0l = *(const v8s*)(Ql + qoff);
    v8s a1l = *(const v8s*)(Ql + qoff + 32);

    // |Q_row|^2: 16 dims/lane, reduce over the 4 lanes sharing l15
    nrm2 = 0.f;
#pragma unroll
    for (int m = 0; m < 8; ++m){
      float x0 = bf2f((u16)a0[m]), x1 = bf2f((u16)a1[m]);
      nrm2 = fmaf(x0, x0, nrm2);
      nrm2 = fmaf(x1, x1, nrm2);
    }
    nrm2 += __shfl_xor(nrm2, 16);
    nrm2 += __shfl_xor(nrm2, 32);     // lane holds |Q_{q0+l15}|^2
    float T0e[4];
#pragma unroll
    for (int e = 0; e < 4; ++e)
      T0e[e] = 0.1875f * sqrtf(__shfl(nrm2, lg*4 + e));   // 1.5*|Q|/8

    int cnt[4] = {0,0,0,0};
#pragma unroll 2
    for (int kt = 0; kt < 16; ++kt){
      int kk0 = w*256 + kt*16;
      const size_t koff = base + (size_t)(kk0 + l15)*64 + lg*8;
      v8s b0  = *(const v8s*)(Kb + koff);
      v8s b1  = *(const v8s*)(Kb + koff + 32);
      v8s b0l = *(const v8s*)(Kl + koff);
      v8s b1l = *(const v8s*)(Kl + koff + 32);
      v4f hh = __builtin_amdgcn_mfma_f32_16x16x32_bf16(a0,  b0,  vzero, 0, 0, 0);
      v4f hl = __builtin_amdgcn_mfma_f32_16x16x32_bf16(a0,  b0l, vzero, 0, 0, 0);
      v4f lh = __builtin_amdgcn_mfma_f32_16x16x32_bf16(a0l, b0,  vzero, 0, 0, 0);
      hh = __builtin_amdgcn_mfma_f32_16x16x32_bf16(a1,  b1,  hh, 0, 0, 0);
      hl = __builtin_amdgcn_mfma_f32_16x16x32_bf16(a1,  b1l, hl, 0, 0, 0);
      lh = __builtin_amdgcn_mfma_f32_16x16x32_bf16(a1l, b1,  lh, 0, 0, 0);
#pragma unroll
      for (int e = 0; e < 4; ++e){
        float sc = ((hh[e] + hl[e]) + lh[e]) * 0.125f;
        bool hit = sc >= T0e[e];
        u64 mk = __ballot(hit);
        u32 nib = (u32)(mk >> (lg*16)) & 0xFFFFu;
        int pos = cnt[e] + (int)__popc(nib & ((1u << l15) - 1u));
        if (hit && pos < 48)
          stageL[(u32)((lg*4 + e)*8 + w)*48u + (u32)pos] =
              ((u32)f2bf(sc) << 16) | (u32)(kk0 + l15);
        cnt[e] += (int)__popc(nib);
      }
    }
    if (l15 == 0){
#pragma unroll
      for (int e = 0; e < 4; ++e){
        int row = lg*4 + e;
        cntL[row*8 + w] = (u32)cnt[e];
        if (cnt[e] > 48) flagL[row] = 1u;
      }
    }
  }
  __syncthreads();   // only block-wide barrier after init

  // ---- Phase 2: owner wave w handles rows R0, R0+1 (interleaved) ----
  const int R0 = w * 2;
  u32 pk0[2], pk1[2], pk2[2], cstore[2], tv[2];
  bool fail[2];

#pragma unroll
  for (int rr = 0; rr < 2; ++rr){
    const int R = R0 + rr;
    uint4 ca = *(const uint4*)&cntL[R*8];
    uint4 cb = *(const uint4*)&cntL[R*8 + 4];
    u32 P1 = ca.x, P2 = P1+ca.y, P3 = P2+ca.z, P4 = P3+ca.w;
    u32 P5 = P4+cb.x, P6 = P5+cb.y, P7 = P6+cb.z;
    cstore[rr] = P7 + cb.w;
    fail[rr] = (flagL[R] != 0u) || (cstore[rr] > 192u);
#pragma unroll
    for (int s = 0; s < 3; ++s){
      u32 idx = (u32)(64*s + lane);
      u32 pb = 0, wsel = 0;
      if (idx >= P1){ pb = P1; wsel = 1; }
      if (idx >= P2){ pb = P2; wsel = 2; }
      if (idx >= P3){ pb = P3; wsel = 3; }
      if (idx >= P4){ pb = P4; wsel = 4; }
      if (idx >= P5){ pb = P5; wsel = 5; }
      if (idx >= P6){ pb = P6; wsel = 6; }
      if (idx >= P7){ pb = P7; wsel = 7; }
      u32 off = idx - pb; off = off > 47u ? 47u : off;
      u32 val = stageL[(u32)(R*8 + (int)wsel)*48u + off];
      val = (idx < cstore[rr]) ? val : 0u;
      if (s == 0) pk0[rr] = val; else if (s == 1) pk1[rr] = val; else pk2[rr] = val;
    }
    tv[rr] = 0u;
  }

  // exact bf16-64th via ballot binsearch (2 rows interleaved)
  for (int bit = 14; bit >= 0; --bit){
#pragma unroll
    for (int rr = 0; rr < 2; ++rr){
      u32 tt = tv[rr] | (1u << bit);
      int c = (int)__popcll(__ballot((pk0[rr] >> 16) >= tt))
            + (int)__popcll(__ballot((pk1[rr] >> 16) >= tt))
            + (int)__popcll(__ballot((pk2[rr] >> 16) >= tt));
      if (c >= 64) tv[rr] = tt;
    }
  }

  // classify into auto / band; write flags
  int na[2], nb[2];
#pragma unroll
  for (int rr = 0; rr < 2; ++rr){
    const int R = R0 + rr;
    float t64f = bf2f((u16)tv[rr]);
    float T0R = 0.1875f * sqrtf(__shfl(nrm2, R));
    float thi = t64f + 0.021f, tlo = t64f - 0.021f;
    int a_ = 0, b_ = 0;
#pragma unroll
    for (int s = 0; s < 3; ++s){
      u32 pkv = (s == 0) ? pk0[rr] : ((s == 1) ? pk1[rr] : pk2[rr]);
      bool act = (u32)(64*s + lane) < cstore[rr];
      float v = bf2f((u16)(pkv >> 16));
      bool aut = act && (v > thi);
      bool ban = act && !aut && (v >= tlo);
      u64 ma = __ballot(aut);
      if (aut){
        int pos = a_ + (int)__popcll(ma & ltmask);
        if (pos < 64) selpL[R*64 + pos] = ((u64)(pkv & 0xFFFF0000u) << 32) | (u64)(pkv & 0x7FFu);
      }
      a_ += (int)__popcll(ma);
      u64 mb = __ballot(ban);
      if (ban){
        int pos = b_ + (int)__popcll(mb & ltmask);
        if (pos < 64) stageL[(u32)(R*8)*48u + (u32)pos] = pkv;   // scratch reuse
      }
      b_ += (int)__popcll(mb);
    }
    bool fl = fail[rr] || (t64f < T0R + 0.025f) || (t64f >= 4.0f) || (b_ > 64);
    fail[rr] = fl;
    if (lane == 0) flags[bh*2048 + q0 + R] = fl ? 1u : 0u;
    na[rr] = fl ? 64 : (a_ > 64 ? 64 : a_);
    nb[rr] = fl ? 0  : b_;
  }
  asm volatile("s_waitcnt lgkmcnt(0)" ::: "memory");
  __builtin_amdgcn_sched_barrier(0);

  // fp64 rescore of band (candidate-per-lane, 2 rows interleaved)
  const double* Kdh = Kd + base;
  const double* Qdh = Qd + base + (size_t)q0*64;
  u32 bpk[2];
#pragma unroll
  for (int rr = 0; rr < 2; ++rr)
    bpk[rr] = (lane < nb[rr]) ? stageL[(u32)((R0+rr)*8)*48u + (u32)lane] : 0u;
  double ac0[2] = {0,0}, ac1[2] = {0,0};
#pragma unroll 4
  for (int j = 0; j < 32; ++j){
#pragma unroll
    for (int rr = 0; rr < 2; ++rr){
      double2 kv = ((const double2*)(Kdh + (size_t)(bpk[rr] & 0x7FFu)*64))[j];
      double2 qv = ((const double2*)(Qdh + (size_t)(R0+rr)*64))[j];
      ac0[rr] = fma(qv.x, kv.x, ac0[rr]);
      ac1[rr] = fma(qv.y, kv.y, ac1[rr]);
    }
  }
  double mv[2]; int mi[2];
#pragma unroll
  for (int rr = 0; rr < 2; ++rr){
    mv[rr] = (lane < nb[rr]) ? (ac0[rr] + ac1[rr]) : -1.0e300;
    mi[rr] = (lane < nb[rr]) ? (int)(bpk[rr] & 0x7FFu) : 0x7FFFFFFF;
  }
  int maxnb = nb[0] > nb[1] ? nb[0] : nb[1];
  int rank[2] = {0,0};
  for (int j = 0; j < maxnb; ++j){
#pragma unroll
    for (int rr = 0; rr < 2; ++rr){
      double ov = __shfl(mv[rr], j); int oi = __shfl(mi[rr], j);
      rank[rr] += (ov > mv[rr] || (ov == mv[rr] && oi < mi[rr])) ? 1 : 0;
    }
  }
#pragma unroll
  for (int rr = 0; rr < 2; ++rr){
    int need = 64 - na[rr]; if (need > nb[rr]) need = nb[rr];
    if (lane < nb[rr] && rank[rr] < need)
      selpL[(R0+rr)*64 + na[rr] + rank[rr]] =
          ((u64)(bpk[rr] & 0xFFFF0000u) << 32) | (u64)(bpk[rr] & 0x7FFu);
  }
  asm volatile("s_waitcnt lgkmcnt(0)" ::: "memory");
  __builtin_amdgcn_sched_barrier(0);

  // softmax over the 64 selected (2 rows interleaved)
  u32 sidx[2]; float scv[2], pp[2];
#pragma unroll
  for (int rr = 0; rr < 2; ++rr){
    u64 pr = selpL[(R0+rr)*64 + lane];
    sidx[rr] = (u32)pr & 0x7FFu;
    scv[rr] = __builtin_bit_cast(float, (u32)(pr >> 32));
  }
#pragma unroll
  for (int rr = 0; rr < 2; ++rr){
    float mx = scv[rr];
#pragma unroll
    for (int off = 32; off; off >>= 1) mx = fmaxf(mx, __shfl_xor(mx, off));
    float p = expf(scv[rr] - mx);
    float Z = p;
#pragma unroll
    for (int off = 32; off; off >>= 1) Z += __shfl_xor(Z, off);
    pp[rr] = p / Z;
  }
#pragma unroll
  for (int rr = 0; rr < 2; ++rr)
    selpL[(R0+rr)*64 + lane] = ((u64)__builtin_bit_cast(u32, pp[rr]) << 32) | (u64)sidx[rr];
  asm volatile("s_waitcnt lgkmcnt(0)" ::: "memory");
  __builtin_amdgcn_sched_barrier(0);

  // PV: 2 dims x 2 sels per lane, uniform-LDS broadcasts (2 rows interleaved)
  const int h = lane >> 5, dl = lane & 31;
  float u0[2] = {0,0}, u1[2] = {0,0};
#pragma unroll 4
  for (int j = 0; j < 64; j += 2){
#pragma unroll
    for (int rr = 0; rr < 2; ++rr){
      u64 pr = selpL[(R0+rr)*64 + j + h];
      float pv = __builtin_bit_cast(float, (u32)(pr >> 32));
      u32 vv = *(const u32*)(Vb + base + (size_t)((u32)pr & 0x7FFu)*64 + 2*dl);
      u0[rr] = fmaf(pv, bf2f((u16)(vv & 0xFFFFu)), u0[rr]);
      u1[rr] = fmaf(pv, bf2f((u16)(vv >> 16)),     u1[rr]);
    }
  }
#pragma unroll
  for (int rr = 0; rr < 2; ++rr){
    u0[rr] += __shfl_xor(u0[rr], 32);
    u1[rr] += __shfl_xor(u1[rr], 32);
  }
  if (lane < 32){
#pragma unroll
    for (int rr = 0; rr < 2; ++rr){
      u32 o = (u32)f2bf(u0[rr]) | ((u32)f2bf(u1[rr]) << 16);
      *(u32*)(Ab + base + (size_t)(q0 + R0 + rr)*64 + 2*dl) = o;
    }
  }
}

// ---------------------------------------------------------------------------
// Exact fallback for flagged rows (~0.4% of rows). One wave per block;
// block handles 16 consecutive global q-rows. Covers ALL 65536 rows.
// ---------------------------------------------------------------------------
__global__ __launch_bounds__(64) void attn_fallback(
    const u32* __restrict__ flags, const double* __restrict__ Qd,
    const double* __restrict__ Kd, const u16* __restrict__ Vb,
    u16* __restrict__ Ab)
{
  __shared__ double valsL[32*64];   // [mm][lane], conflict-free
  const int blk = blockIdx.x;
  const int lane = threadIdx.x;
  u32 f = (lane < 16) ? flags[blk*16 + lane] : 0u;
  u64 msk = __ballot(f != 0u);
  if (msk == 0ull) return;
  for (int i = 0; i < 16; ++i){
    if (!((msk >> i) & 1ull)) continue;
    int g = blk*16 + i;
    int bh = g >> 11, qrow = g & 2047;
    size_t base = (size_t)(bh >> 4)*2097152 + (size_t)(bh & 15)*131072;
    const double* Qrow = Qd + base + (size_t)qrow*64;
    for (int mm = 0; mm < 32; ++mm){
      const double* Kr = Kd + base + ((size_t)lane*32 + mm)*64;
      double s0 = 0.0, s1 = 0.0;
      for (int j = 0; j < 32; ++j){
        s0 = fma(Qrow[2*j],   Kr[2*j],   s0);
        s1 = fma(Qrow[2*j+1], Kr[2*j+1], s1);
      }
      valsL[mm*64 + lane] = (s0 + s1) * 0.125;
    }
    // iterative exact top-64 (desc value, asc index)
    double selv = 0.0; int seli = 0;
    double pvv = 1.0e300; int pii = -1;
    for (int step = 0; step < 64; ++step){
      double bv = -1.0e300; int bi = 0x7FFFFFFF;
      for (int mm = 0; mm < 32; ++mm){
        double vv = valsL[mm*64 + lane];
        int col = lane*32 + mm;
        bool after = (vv < pvv) || (vv == pvv && col > pii);
        bool bet = after && (vv > bv || (vv == bv && col < bi));
        bv = bet ? vv : bv;
        bi = bet ? col : bi;
      }
#pragma unroll
      for (int off = 32; off; off >>= 1){
        double ov = __shfl_xor(bv, off); int oi = __shfl_xor(bi, off);
        bool tk = (ov > bv) || (ov == bv && oi < bi);
        bv = tk ? ov : bv; bi = tk ? oi : bi;
      }
      if (lane == step){ selv = bv; seli = bi; }
      pvv = bv; pii = bi;
    }
    // softmax over lane-held selected scores
    float sc = (float)selv;
    float mx = sc;
#pragma unroll
    for (int off = 32; off; off >>= 1) mx = fmaxf(mx, __shfl_xor(mx, off));
    float p = expf(sc - mx);
    float Z = p;
#pragma unroll
    for (int off = 32; off; off >>= 1) Z += __shfl_xor(Z, off);
    float pp = p / Z;
    // PV: lane = d
    float o = 0.f;
    for (int j = 0; j < 64; ++j){
      float pj = __shfl(pp, j); int ij = __shfl(seli, j);
      o += pj * bf2f(Vb[base + (size_t)ij*64 + lane]);
    }
    Ab[base + (size_t)qrow*64 + lane] = f2bf(o);
  }
}

// ---------------------------------------------------------------------------
extern "C" void kernel_launch(void* const* d_in, const int* in_sizes, int n_in,
                              void* d_out, int out_size, void* d_ws, size_t ws_size,
                              hipStream_t stream)
{
  (void)in_sizes; (void)n_in; (void)out_size; (void)ws_size;
  const float* q  = (const float*)d_in[0];
  const float* k  = (const float*)d_in[1];
  const float* v  = (const float*)d_in[2];
  const float* Wq = (const float*)d_in[3];
  const float* bq = (const float*)d_in[4];
  const float* Wk = (const float*)d_in[5];
  const float* bk = (const float*)d_in[6];
  const float* Wv = (const float*)d_in[7];
  const float* bv = (const float*)d_in[8];
  const float* Wo = (const float*)d_in[9];
  const float* bo = (const float*)d_in[10];

  char* ws = (char*)d_ws;
  const size_t MB = 1048576;
  double* Qd  = (double*)(ws);             // 32 MB
  double* Kd  = (double*)(ws + 32*MB);     // 32 MB
  u16*    Qb  = (u16*)  (ws + 64*MB);      // 8 MB  (hi)
  u16*    Kb  = (u16*)  (ws + 72*MB);      // 8 MB  (hi)
  u16*    Ql  = (u16*)  (ws + 80*MB);      // 8 MB  (lo)
  u16*    Kl  = (u16*)  (ws + 88*MB);      // 8 MB  (lo)
  u16*    Abf = (u16*)  (ws + 96*MB);      // 8 MB
  s8*     dact= (s8*)   (ws + 104*MB);     // 16 MB (dead after K-proj)
  u16*    Vbf = (u16*)  (ws + 104*MB);     // 8 MB  (aliases dact, written after)
  s8*     dw  = (s8*)   (ws + 120*MB);     // 4 MB  (dead after K-proj)
  u32*    flg = (u32*)  (ws + 120*MB);     // 256 KB (aliases dw, written after)

  quant_digits<<<2048, 256, 0, stream>>>(q,  dact, 4194304, 134217728.0f, 7.75f);    // 2^27
  quant_digits<<<512,  256, 0, stream>>>(Wq, dw,   1048576, 4294967296.0f, 0.2495f); // 2^32
  gemm_i8<<<dim3(128, 32), 256, 0, stream>>>(dact, dw, bq, Qd, Qb, Ql);
  quant_digits<<<2048, 256, 0, stream>>>(k,  dact, 4194304, 134217728.0f, 7.75f);
  quant_digits<<<512,  256, 0, stream>>>(Wk, dw,   1048576, 4294967296.0f, 0.2495f);
  gemm_i8<<<dim3(128, 32), 256, 0, stream>>>(dact, dw, bk, Kd, Kb, Kl);
  gemm_bf16k<0,1><<<dim3(128, 32), 256, 0, stream>>>(v, Wv, bv, Vbf);
  attn_topk<<<dim3(128, 32), 512, 0, stream>>>(Qb, Kb, Ql, Kl, Qd, Kd, Vbf, Abf, flg);
  attn_fallback<<<4096, 64, 0, stream>>>(flg, Qd, Kd, Vbf, Abf);
  gemm_bf16k<1,0><<<dim3(128, 32), 256, 0, stream>>>(Abf, Wo, bo, d_out);
}